// Round 10
// baseline (1985.284 us; speedup 1.0000x reference)
//
#include <hip/hip_runtime.h>

// MoleculeGCN: 2-layer GCN, N=100000, 128->64->64, E=1600000 + self-loops.
// r10 = r9 with the wave-partition bug fixed in agg_kernel (r9: all 4 waves
// of a block processed the SAME records -> every edge added 4x, absmax 6.5).
// Design recap:
//  - r6 lesson: random 8B scatter = one 64B line per record (102MB).
//  - r8 lesson: blockIdx%8 does not control XCD placement; shared lines get
//    worse (114MB). => every output line single-owner by construction.
// Pipeline: histA (per-block padded bin hist, LDS) -> scan -> scatter (dense
// per-(bin,block) 64B-aligned ranges, LDS cursors, sentinel padding) ->
// degdinv -> gemm1 -> aggLDS1 -> gemm2 -> aggLDS2.
// Aggregation: block per 128-node bucket, LDS fp32 accumulator (atomic adds,
// bank-swizzled), waves own disjoint 64-record chunks (stride 256).

#define NB_SCAT 64      // blocks owning edge chunks (hist/scatter)
#define BUCKET 128      // nodes per bucket (pow2: bucket=d>>7, dloc=d&127)
#define PADREC 16       // 4B recs per 64B line; cell padding granularity
#define SCAN_BS 256
#define INVALID_BIT (1u << 27)
#define SRC_MASK 0xFFFFFu

// ---------- edge dtype detect (int64 vs int32), SAMPLED ----------
__global__ __launch_bounds__(256) void detect_dtype_kernel(const unsigned* __restrict__ w,
                                                           int E, unsigned* __restrict__ flag) {
  __shared__ unsigned sacc;
  if (threadIdx.x == 0) sacc = 0u;
  __syncthreads();
  int ns = min(16384, E);
  unsigned acc = 0;
  for (int i = threadIdx.x; i < ns; i += 256) acc |= w[2 * i + 1];
  if (__any(acc != 0) && (threadIdx.x & 63) == 0) sacc = 1u;
  __syncthreads();
  if (threadIdx.x == 0) *flag = sacc;
}

__device__ __forceinline__ int edge_src(const int* w, int e, int E, bool is64) {
  return is64 ? w[2 * (long)e] : w[e];
}
__device__ __forceinline__ int edge_dst(const int* w, int e, int E, bool is64) {
  return is64 ? w[2 * ((long)E + e)] : w[(long)E + e];
}

// ---------- pass A1: per-(bin,block) PADDED histogram, layout [bin][block] ----------
__global__ __launch_bounds__(256) void histA_kernel(const int* __restrict__ w, int E,
                                                    const unsigned* __restrict__ flag,
                                                    int nbuck, int* __restrict__ hist) {
  __shared__ int h[1024];  // nbuck <= 1024 (N <= 131072)
  bool is64 = (*flag == 0u);
  int i = blockIdx.x;
  int CH = (E + NB_SCAT - 1) / NB_SCAT;
  int e0 = i * CH, e1 = min(E, e0 + CH);
  for (int b = threadIdx.x; b < nbuck; b += 256) h[b] = 0;
  __syncthreads();
  for (int e = e0 + threadIdx.x; e < e1; e += 256)
    atomicAdd(&h[edge_dst(w, e, E, is64) >> 7], 1);
  __syncthreads();
  for (int b = threadIdx.x; b < nbuck; b += 256)
    hist[b * NB_SCAT + i] = (h[b] + PADREC - 1) & ~(PADREC - 1);  // 64B-pad cells
}

// ---------- scan (3 kernels, flat over nbuck*NB_SCAT, sentinel=total) ----------
__global__ void scan_block_kernel(const int* __restrict__ cnt, int n, int* __restrict__ bsums) {
  __shared__ int s[SCAN_BS];
  int gid = blockIdx.x * SCAN_BS + threadIdx.x;
  s[threadIdx.x] = (gid < n) ? cnt[gid] : 0;
  __syncthreads();
  for (int st = SCAN_BS / 2; st > 0; st >>= 1) {
    if (threadIdx.x < st) s[threadIdx.x] += s[threadIdx.x + st];
    __syncthreads();
  }
  if (threadIdx.x == 0) bsums[blockIdx.x] = s[0];
}

__global__ __launch_bounds__(512) void scan_bsums_kernel(int* __restrict__ bsums, int nb) {
  __shared__ int s[512];
  int carry = 0;
  for (int base = 0; base < nb; base += 512) {
    int g = base + threadIdx.x;
    int v = (g < nb) ? bsums[g] : 0;
    s[threadIdx.x] = v;
    __syncthreads();
    for (int st = 1; st < 512; st <<= 1) {
      int t = (threadIdx.x >= st) ? s[threadIdx.x - st] : 0;
      __syncthreads();
      s[threadIdx.x] += t;
      __syncthreads();
    }
    if (g < nb) bsums[g] = carry + s[threadIdx.x] - v;
    carry += s[511];
    __syncthreads();
  }
}

__global__ void scan_apply_kernel(const int* __restrict__ cnt, int n,
                                  const int* __restrict__ bsums, int* __restrict__ out) {
  __shared__ int s[SCAN_BS];
  int gid = blockIdx.x * SCAN_BS + threadIdx.x;
  int v = (gid < n) ? cnt[gid] : 0;
  s[threadIdx.x] = v;
  __syncthreads();
  for (int st = 1; st < SCAN_BS; st <<= 1) {
    int t = (threadIdx.x >= st) ? s[threadIdx.x - st] : 0;
    __syncthreads();
    s[threadIdx.x] += t;
    __syncthreads();
  }
  if (gid < n) {
    int ex = bsums[blockIdx.x] + s[threadIdx.x] - v;
    out[gid] = ex;
    if (gid == n - 1) out[n] = ex + v;  // sentinel = total padded records
  }
}

// ---------- pass A3: scatter to dense per-(bin,block) ranges ----------
// Each range is written by ONE block (single-owner lines; cells are 64B-aligned
// because every padded cell size is a multiple of 16 records). LDS cursors.
__global__ __launch_bounds__(256) void scatter_kernel(const int* __restrict__ w, int E,
                                                      const unsigned* __restrict__ flag,
                                                      int nbuck, const int* __restrict__ shist,
                                                      unsigned* __restrict__ arr) {
  __shared__ int cur[1024];
  bool is64 = (*flag == 0u);
  int i = blockIdx.x;
  for (int b = threadIdx.x; b < nbuck; b += 256) cur[b] = shist[b * NB_SCAT + i];
  __syncthreads();
  int CH = (E + NB_SCAT - 1) / NB_SCAT;
  int e0 = i * CH, e1 = min(E, e0 + CH);
  for (int e = e0 + threadIdx.x; e < e1; e += 256) {
    int s = edge_src(w, e, E, is64);
    int d = edge_dst(w, e, E, is64);
    int p = atomicAdd(&cur[d >> 7], 1);  // LDS atomic
    arr[p] = (unsigned)s | ((unsigned)(d & 127) << 20);
  }
  __syncthreads();
  for (int b = threadIdx.x; b < nbuck; b += 256) {
    int endp = shist[b * NB_SCAT + i + 1];  // flat next cell (contiguous layout)
    for (int p = cur[b]; p < endp; p++) arr[p] = INVALID_BIT;  // zero-contribution
  }
}

// ---------- degrees -> dinv, per bucket (LDS hist, no global atomics) ----------
__global__ __launch_bounds__(256) void degdinv_kernel(const unsigned* __restrict__ arr,
                                                      const int* __restrict__ shist,
                                                      int N, float* __restrict__ dinv) {
  __shared__ int cnt[BUCKET];
  int b = blockIdx.x;
  for (int t = threadIdx.x; t < BUCKET; t += 256) cnt[t] = 0;
  __syncthreads();
  int eb = shist[b * NB_SCAT], ee = shist[(b + 1) * NB_SCAT];
  for (int p = eb + threadIdx.x; p < ee; p += 256) {
    unsigned r = arr[p];
    if (!(r & INVALID_BIT)) atomicAdd(&cnt[(r >> 20) & 127], 1);
  }
  __syncthreads();
  int g = b * BUCKET + threadIdx.x;
  if (threadIdx.x < BUCKET && g < N) dinv[g] = rsqrtf((float)cnt[threadIdx.x] + 1.0f);
}

// ---------- GEMM: H[n][64] = X[n][K] @ W[K][64], W staged in LDS (r6 proven) ----------
template <int K>
__global__ __launch_bounds__(256) void gemm_kernel(const float* __restrict__ X,
                                                   const float* __restrict__ W,
                                                   float* __restrict__ H, int n) {
  __shared__ float Ws[K * 64];
  for (int i = threadIdx.x; i < K * 64; i += 256) Ws[i] = W[i];
  __syncthreads();
  int row = blockIdx.x * 256 + threadIdx.x;
  if (row >= n) return;
  const float4* xr = (const float4*)(X + (size_t)row * K);
  float acc[64];
#pragma unroll
  for (int c = 0; c < 64; c++) acc[c] = 0.f;
#pragma unroll 4
  for (int k4 = 0; k4 < K / 4; k4++) {
    float4 xv = xr[k4];
#pragma unroll
    for (int kk = 0; kk < 4; kk++) {
      float xs = (kk == 0) ? xv.x : (kk == 1) ? xv.y : (kk == 2) ? xv.z : xv.w;
      const float4* wr = (const float4*)&Ws[(k4 * 4 + kk) * 64];
#pragma unroll
      for (int c4 = 0; c4 < 16; c4++) {
        float4 wv = wr[c4];
        acc[c4 * 4 + 0] += xs * wv.x;
        acc[c4 * 4 + 1] += xs * wv.y;
        acc[c4 * 4 + 2] += xs * wv.z;
        acc[c4 * 4 + 3] += xs * wv.w;
      }
    }
  }
  float4* ho = (float4*)(H + (size_t)row * 64);
#pragma unroll
  for (int c4 = 0; c4 < 16; c4++) {
    float4 v;
    v.x = acc[c4 * 4 + 0]; v.y = acc[c4 * 4 + 1];
    v.z = acc[c4 * 4 + 2]; v.w = acc[c4 * 4 + 3];
    ho[c4] = v;
  }
}

// ---------- aggregation: block per bucket, LDS fp32 accumulator ----------
// FIX vs r9: waves own DISJOINT 64-record chunks (base = eb + wave*64, stride
// 256). r9 had all 4 waves processing the same records -> 4x over-count.
// Within a wave: grp=lane>>4 takes records at idx%4==grp, fl=lane&15 owns one
// float4 of the row; 8-deep gather pipeline (32 records in flight per wave).
__global__ __launch_bounds__(256) void agg_kernel(
    const float4* __restrict__ H4, const unsigned* __restrict__ arr,
    const int* __restrict__ shist, const float* __restrict__ dinv,
    const float* __restrict__ bias, float* __restrict__ OUT, int N, int relu) {
  __shared__ float acc[BUCKET * 64];  // 32KB -> 4 blocks/CU
  __shared__ float dl[BUCKET];
  int b = blockIdx.x;
  int d0 = b * BUCKET;
  for (int t = threadIdx.x; t < BUCKET * 16; t += 256)
    ((float4*)acc)[t] = make_float4(0.f, 0.f, 0.f, 0.f);
  for (int t = threadIdx.x; t < BUCKET; t += 256) {
    int g = d0 + t;
    dl[t] = (g < N) ? dinv[g] : 0.f;
  }
  __syncthreads();
  int eb = shist[b * NB_SCAT], ee = shist[(b + 1) * NB_SCAT];
  int lane = threadIdx.x & 63, grp = lane >> 4, fl = lane & 15;
  int wave = threadIdx.x >> 6;
  for (int base = eb + wave * 64; base < ee; base += 256) {  // per-wave chunks
    int m = min(64, ee - base);
    unsigned rl = INVALID_BIT;
    float nl = 0.f;
    if (lane < m) {
      rl = arr[base + lane];  // coalesced 4B
      if (!(rl & INVALID_BIT))
        nl = dinv[rl & SRC_MASK] * dl[(rl >> 20) & 127];
    }
    int iters = ((m + 31) >> 5) << 3;  // 8 or 16 steps; each step covers 4 records
    for (int j0 = 0; j0 < iters; j0 += 8) {
      unsigned r[8]; float w[8]; float4 h[8];
#pragma unroll
      for (int t = 0; t < 8; t++) {
        int idx = (j0 + t) * 4 + grp;
        r[t] = __shfl((int)rl, idx);
        w[t] = __shfl(nl, idx);
      }
#pragma unroll
      for (int t = 0; t < 8; t++) h[t] = H4[(size_t)(r[t] & SRC_MASK) * 16 + fl];
#pragma unroll
      for (int t = 0; t < 8; t++) {
        int dloc = (r[t] >> 20) & 127;
        int sw = (dloc & 3) << 3;  // bank spread
        float* a = &acc[dloc * 64];
        int cb = fl * 4;
        atomicAdd(&a[(cb + 0) ^ sw], h[t].x * w[t]);
        atomicAdd(&a[(cb + 1) ^ sw], h[t].y * w[t]);
        atomicAdd(&a[(cb + 2) ^ sw], h[t].z * w[t]);
        atomicAdd(&a[(cb + 3) ^ sw], h[t].w * w[t]);
      }
    }
  }
  __syncthreads();
  // epilogue: thread t -> node i=t>>1, half=t&1 -> cols [half*32, half*32+32)
  int i = threadIdx.x >> 1, half = threadIdx.x & 1;
  int g = d0 + i;
  if (g < N) {
    float d2 = dl[i] * dl[i];
    int sw = (i & 3) << 3;
#pragma unroll
    for (int c4 = 0; c4 < 8; c4++) {
      int col = half * 32 + c4 * 4;
      float4 av = *(float4*)&acc[i * 64 + (col ^ sw)];  // (col+j)^sw == (col^sw)+j
      float4 hv = ((const float4*)H4)[(size_t)g * 16 + (col >> 2)];
      float4 bv = *(const float4*)&bias[col];
      float4 o;
      o.x = av.x + hv.x * d2 + bv.x;
      o.y = av.y + hv.y * d2 + bv.y;
      o.z = av.z + hv.z * d2 + bv.z;
      o.w = av.w + hv.w * d2 + bv.w;
      if (relu) {
        o.x = fmaxf(o.x, 0.f); o.y = fmaxf(o.y, 0.f);
        o.z = fmaxf(o.z, 0.f); o.w = fmaxf(o.w, 0.f);
      }
      *(float4*)&OUT[(size_t)g * 64 + col] = o;  // coalesced
    }
  }
}

extern "C" void kernel_launch(void* const* d_in, const int* in_sizes, int n_in,
                              void* d_out, int out_size, void* d_ws, size_t ws_size,
                              hipStream_t stream) {
  const float* x  = (const float*)d_in[0];
  const int*   ei = (const int*)d_in[1];
  const float* W1 = (const float*)d_in[2];
  const float* b1 = (const float*)d_in[3];
  const float* W2 = (const float*)d_in[4];
  const float* b2 = (const float*)d_in[5];
  float* out = (float*)d_out;

  const int N = in_sizes[0] / 128;
  const int E = in_sizes[1] / 2;
  const int nbuck = (N + BUCKET - 1) / BUCKET;    // 782
  const int L = nbuck * NB_SCAT;                  // flat hist length

  // ---- workspace carve-up (256B aligned) ----
  size_t off = 0;
  char* base = (char*)d_ws;
  auto alloc = [&](size_t bytes) -> void* {
    void* p = base + off;
    off += (bytes + 255) & ~(size_t)255;
    return p;
  };
  unsigned* flag  = (unsigned*)alloc(256);  // zeroed
  size_t zero_bytes = off;
  int*      hist  = (int*)alloc((size_t)L * 4);
  int*      shist = (int*)alloc((size_t)(L + 1) * 4);
  int nb = (L + SCAN_BS - 1) / SCAN_BS;
  int*      bsums = (int*)alloc((size_t)nb * 4);
  unsigned* arr   = (unsigned*)alloc(((size_t)E + (size_t)PADREC * L) * 4);
  float*    dinv  = (float*)alloc((size_t)N * 4);
  float*    h1    = (float*)alloc((size_t)N * 64 * 4);
  float*    a1    = (float*)alloc((size_t)N * 64 * 4);
  float*    h2    = h1;  // h1 dead after first aggregation

  hipMemsetAsync(d_ws, 0, zero_bytes, stream);

  int gemm_blocks = (N + 255) / 256;

  // ---- graph prep: bucket sort (shared by both layers) ----
  detect_dtype_kernel<<<1, 256, 0, stream>>>((const unsigned*)ei, E, flag);
  histA_kernel<<<NB_SCAT, 256, 0, stream>>>(ei, E, flag, nbuck, hist);
  scan_block_kernel<<<nb, SCAN_BS, 0, stream>>>(hist, L, bsums);
  scan_bsums_kernel<<<1, 512, 0, stream>>>(bsums, nb);
  scan_apply_kernel<<<nb, SCAN_BS, 0, stream>>>(hist, L, bsums, shist);
  scatter_kernel<<<NB_SCAT, 256, 0, stream>>>(ei, E, flag, nbuck, shist, arr);
  degdinv_kernel<<<nbuck, 256, 0, stream>>>(arr, shist, N, dinv);

  // ---- layer 1 ----
  gemm_kernel<128><<<gemm_blocks, 256, 0, stream>>>(x, W1, h1, N);
  agg_kernel<<<nbuck, 256, 0, stream>>>((const float4*)h1, arr, shist, dinv, b1, a1, N, 1);

  // ---- layer 2 ----
  gemm_kernel<64><<<gemm_blocks, 256, 0, stream>>>(a1, W2, h2, N);
  agg_kernel<<<nbuck, 256, 0, stream>>>((const float4*)h2, arr, shist, dinv, b2, out, N, 0);
}

// Round 11
// 404.968 us; speedup vs baseline: 4.9023x; 4.9023x over previous
//
#include <hip/hip_runtime.h>

// MoleculeGCN: 2-layer GCN, N=100000, 128->64->64, E=1600000 + self-loops.
// r11 hybrid: r6's proven compute path (wave-per-node float4 aggregate, 25000
// blocks of TLP; LDS-broadcast GEMMs) + r10's proven single-owner scatter
// machinery to build the CSR without the 102MB line-amplified random scatter.
// Lessons enforced:
//  - r6/r8: every scatter-output line must be written by ONE block.
//  - r10: never shrink the grid for latency-bound gathers (the LDS-accum agg
//    at 782 blocks ran at 257 GB/s vs 2270 at 100K waves).
// Pipeline: detect -> histA -> scan(L) -> scatter(binned, single-owner) ->
// degcnt -> scan(N)+dinv -> place(bucket-window CSR, single-owner) ->
// gemm1 -> agg1 -> gemm2 -> agg2.

#define NB_SCAT 64      // blocks owning edge chunks (hist/scatter)
#define BUCKET 128      // nodes per bucket (pow2: bucket=d>>7, dloc=d&127)
#define PADREC 16       // 4B recs per 64B line; cell padding granularity
#define SCAN_BS 256
#define INVALID_BIT (1u << 27)
#define SRC_MASK 0xFFFFFu

// ---------- edge dtype detect (int64 vs int32), SAMPLED ----------
__global__ __launch_bounds__(256) void detect_dtype_kernel(const unsigned* __restrict__ w,
                                                           int E, unsigned* __restrict__ flag) {
  __shared__ unsigned sacc;
  if (threadIdx.x == 0) sacc = 0u;
  __syncthreads();
  int ns = min(16384, E);
  unsigned acc = 0;
  for (int i = threadIdx.x; i < ns; i += 256) acc |= w[2 * i + 1];
  if (__any(acc != 0) && (threadIdx.x & 63) == 0) sacc = 1u;
  __syncthreads();
  if (threadIdx.x == 0) *flag = sacc;
}

__device__ __forceinline__ int edge_src(const int* w, int e, int E, bool is64) {
  return is64 ? w[2 * (long)e] : w[e];
}
__device__ __forceinline__ int edge_dst(const int* w, int e, int E, bool is64) {
  return is64 ? w[2 * ((long)E + e)] : w[(long)E + e];
}

// ---------- per-(bucket,block) PADDED histogram, layout [bucket][block] ----------
__global__ __launch_bounds__(256) void histA_kernel(const int* __restrict__ w, int E,
                                                    const unsigned* __restrict__ flag,
                                                    int nbuck, int* __restrict__ hist) {
  __shared__ int h[1024];  // nbuck <= 1024 (N <= 131072)
  bool is64 = (*flag == 0u);
  int i = blockIdx.x;
  int CH = (E + NB_SCAT - 1) / NB_SCAT;
  int e0 = i * CH, e1 = min(E, e0 + CH);
  for (int b = threadIdx.x; b < nbuck; b += 256) h[b] = 0;
  __syncthreads();
  for (int e = e0 + threadIdx.x; e < e1; e += 256)
    atomicAdd(&h[edge_dst(w, e, E, is64) >> 7], 1);
  __syncthreads();
  for (int b = threadIdx.x; b < nbuck; b += 256)
    hist[b * NB_SCAT + i] = (h[b] + PADREC - 1) & ~(PADREC - 1);  // 64B-pad cells
}

// ---------- generic exclusive scan (3 kernels, + sentinel out[n]=total) ----------
__global__ void scan_block_kernel(const int* __restrict__ cnt, int n, int* __restrict__ bsums) {
  __shared__ int s[SCAN_BS];
  int gid = blockIdx.x * SCAN_BS + threadIdx.x;
  s[threadIdx.x] = (gid < n) ? cnt[gid] : 0;
  __syncthreads();
  for (int st = SCAN_BS / 2; st > 0; st >>= 1) {
    if (threadIdx.x < st) s[threadIdx.x] += s[threadIdx.x + st];
    __syncthreads();
  }
  if (threadIdx.x == 0) bsums[blockIdx.x] = s[0];
}

__global__ __launch_bounds__(512) void scan_bsums_kernel(int* __restrict__ bsums, int nb) {
  __shared__ int s[512];
  int carry = 0;
  for (int base = 0; base < nb; base += 512) {
    int g = base + threadIdx.x;
    int v = (g < nb) ? bsums[g] : 0;
    s[threadIdx.x] = v;
    __syncthreads();
    for (int st = 1; st < 512; st <<= 1) {
      int t = (threadIdx.x >= st) ? s[threadIdx.x - st] : 0;
      __syncthreads();
      s[threadIdx.x] += t;
      __syncthreads();
    }
    if (g < nb) bsums[g] = carry + s[threadIdx.x] - v;
    carry += s[511];
    __syncthreads();
  }
}

// out = exclusive scan of cnt (+ out[n] = total). If dinv != nullptr, also
// dinv[gid] = rsqrt(cnt+1) (the +1 is the self loop).
__global__ void scan_apply_kernel(const int* __restrict__ cnt, int n,
                                  const int* __restrict__ bsums, int* __restrict__ out,
                                  float* __restrict__ dinv) {
  __shared__ int s[SCAN_BS];
  int gid = blockIdx.x * SCAN_BS + threadIdx.x;
  int v = (gid < n) ? cnt[gid] : 0;
  s[threadIdx.x] = v;
  __syncthreads();
  for (int st = 1; st < SCAN_BS; st <<= 1) {
    int t = (threadIdx.x >= st) ? s[threadIdx.x - st] : 0;
    __syncthreads();
    s[threadIdx.x] += t;
    __syncthreads();
  }
  if (gid < n) {
    int ex = bsums[blockIdx.x] + s[threadIdx.x] - v;
    out[gid] = ex;
    if (dinv) dinv[gid] = rsqrtf((float)v + 1.0f);
    if (gid == n - 1) out[n] = ex + v;  // sentinel
  }
}

// ---------- scatter to dense per-(bucket,block) ranges (single-owner) ----------
__global__ __launch_bounds__(256) void scatter_kernel(const int* __restrict__ w, int E,
                                                      const unsigned* __restrict__ flag,
                                                      int nbuck, const int* __restrict__ shist,
                                                      unsigned* __restrict__ arr) {
  __shared__ int cur[1024];
  bool is64 = (*flag == 0u);
  int i = blockIdx.x;
  for (int b = threadIdx.x; b < nbuck; b += 256) cur[b] = shist[b * NB_SCAT + i];
  __syncthreads();
  int CH = (E + NB_SCAT - 1) / NB_SCAT;
  int e0 = i * CH, e1 = min(E, e0 + CH);
  for (int e = e0 + threadIdx.x; e < e1; e += 256) {
    int s = edge_src(w, e, E, is64);
    int d = edge_dst(w, e, E, is64);
    int p = atomicAdd(&cur[d >> 7], 1);  // LDS cursor
    arr[p] = (unsigned)s | ((unsigned)(d & 127) << 20);
  }
  __syncthreads();
  for (int b = threadIdx.x; b < nbuck; b += 256) {
    int endp = shist[b * NB_SCAT + i + 1];
    for (int p = cur[b]; p < endp; p++) arr[p] = INVALID_BIT;  // sentinel fill
  }
}

// ---------- per-node degree counts from the binned array (no global atomics) ----
__global__ __launch_bounds__(256) void degcnt_kernel(const unsigned* __restrict__ arr,
                                                     const int* __restrict__ shist,
                                                     int N, int* __restrict__ cnt) {
  __shared__ int c[BUCKET];
  int b = blockIdx.x;
  for (int t = threadIdx.x; t < BUCKET; t += 256) c[t] = 0;
  __syncthreads();
  int eb = shist[b * NB_SCAT], ee = shist[(b + 1) * NB_SCAT];
  for (int p = eb + threadIdx.x; p < ee; p += 256) {
    unsigned r = arr[p];
    if (!(r & INVALID_BIT)) atomicAdd(&c[(r >> 20) & 127], 1);
  }
  __syncthreads();
  int g = b * BUCKET + threadIdx.x;
  if (threadIdx.x < BUCKET && g < N) cnt[g] = c[threadIdx.x];
}

// ---------- place: bucket-window CSR build (single-owner lines) ----------
// Block b owns CSR window [offs[b*128], offs[(b+1)*128)) ~16KB: all its lines
// are written only by this block -> L2 accumulates full lines (r6's random
// version: 102MB writeback for a 12.8MB payload).
__global__ __launch_bounds__(256) void place_kernel(
    const unsigned* __restrict__ arr, const int* __restrict__ shist,
    const int* __restrict__ offs, const float* __restrict__ dinv,
    int N, int2* __restrict__ csr) {
  __shared__ int lfill[BUCKET];
  __shared__ int loffs[BUCKET];
  __shared__ float dl[BUCKET];
  int b = blockIdx.x, d0 = b * BUCKET;
  for (int t = threadIdx.x; t < BUCKET; t += 256) {
    lfill[t] = 0;
    int g = d0 + t;
    loffs[t] = (g < N) ? offs[g] : 0;
    dl[t] = (g < N) ? dinv[g] : 0.f;
  }
  __syncthreads();
  int eb = shist[b * NB_SCAT], ee = shist[(b + 1) * NB_SCAT];
  for (int p = eb + threadIdx.x; p < ee; p += 256) {
    unsigned r = arr[p];
    if (r & INVALID_BIT) continue;
    int s = r & SRC_MASK;
    int dloc = (r >> 20) & 127;
    int pos = loffs[dloc] + atomicAdd(&lfill[dloc], 1);
    int2 rec;
    rec.x = s;
    rec.y = __float_as_int(dinv[s] * dl[dloc]);
    csr[pos] = rec;
  }
}

// ---------- GEMM: H[n][64] = X[n][K] @ W[K][64], W staged in LDS (r6 proven) ----------
template <int K>
__global__ __launch_bounds__(256) void gemm_kernel(const float* __restrict__ X,
                                                   const float* __restrict__ W,
                                                   float* __restrict__ H, int n) {
  __shared__ float Ws[K * 64];
  for (int i = threadIdx.x; i < K * 64; i += 256) Ws[i] = W[i];
  __syncthreads();
  int row = blockIdx.x * 256 + threadIdx.x;
  if (row >= n) return;
  const float4* xr = (const float4*)(X + (size_t)row * K);
  float acc[64];
#pragma unroll
  for (int c = 0; c < 64; c++) acc[c] = 0.f;
#pragma unroll 4
  for (int k4 = 0; k4 < K / 4; k4++) {
    float4 xv = xr[k4];
#pragma unroll
    for (int kk = 0; kk < 4; kk++) {
      float xs = (kk == 0) ? xv.x : (kk == 1) ? xv.y : (kk == 2) ? xv.z : xv.w;
      const float4* wr = (const float4*)&Ws[(k4 * 4 + kk) * 64];
#pragma unroll
      for (int c4 = 0; c4 < 16; c4++) {
        float4 wv = wr[c4];  // same address across lanes -> LDS broadcast
        acc[c4 * 4 + 0] += xs * wv.x;
        acc[c4 * 4 + 1] += xs * wv.y;
        acc[c4 * 4 + 2] += xs * wv.z;
        acc[c4 * 4 + 3] += xs * wv.w;
      }
    }
  }
  float4* ho = (float4*)(H + (size_t)row * 64);
#pragma unroll
  for (int c4 = 0; c4 < 16; c4++) {
    float4 v;
    v.x = acc[c4 * 4 + 0]; v.y = acc[c4 * 4 + 1];
    v.z = acc[c4 * 4 + 2]; v.w = acc[c4 * 4 + 3];
    ho[c4] = v;
  }
}

// ---------- aggregation (r6 proven): wave per node, 4 groups x 16 lanes x float4 ----
__global__ __launch_bounds__(256) void aggregate_kernel(
    const float4* __restrict__ H4, const int* __restrict__ offs,
    const int2* __restrict__ csr,
    const float* __restrict__ dinv, const float4* __restrict__ bias4,
    float4* __restrict__ OUT4, int n, int relu) {
  int wid = (blockIdx.x * 256 + threadIdx.x) >> 6;
  int lane = threadIdx.x & 63;
  if (wid >= n) return;
  int grp = lane >> 4;
  int fl = lane & 15;
  int beg = offs[wid];
  int end = offs[wid + 1];
  float4 acc = {0.f, 0.f, 0.f, 0.f};
  for (int base = beg; base < end; base += 64) {
    int m = min(64, end - base);
    int sl = 0; float nl = 0.f;
    if (lane < m) {
      int2 rec = csr[base + lane];  // coalesced 8B
      sl = rec.x;
      nl = __int_as_float(rec.y);
    }
    int iters = ((m + 31) >> 5) << 3;  // 8 or 16; each iter covers 4 edges
    for (int j0 = 0; j0 < iters; j0 += 8) {
      int s[8]; float w[8]; float4 h[8];
#pragma unroll
      for (int t = 0; t < 8; t++) {
        int idx = (j0 + t) * 4 + grp;  // uniform within each 16-lane group
        s[t] = __shfl(sl, idx);
        w[t] = __shfl(nl, idx);
      }
#pragma unroll
      for (int t = 0; t < 8; t++) h[t] = H4[(size_t)s[t] * 16 + fl];  // 8 in flight
#pragma unroll
      for (int t = 0; t < 8; t++) {
        acc.x += h[t].x * w[t];
        acc.y += h[t].y * w[t];
        acc.z += h[t].z * w[t];
        acc.w += h[t].w * w[t];
      }
    }
  }
#pragma unroll
  for (int off2 = 32; off2 >= 16; off2 >>= 1) {
    acc.x += __shfl_xor(acc.x, off2);
    acc.y += __shfl_xor(acc.y, off2);
    acc.z += __shfl_xor(acc.z, off2);
    acc.w += __shfl_xor(acc.w, off2);
  }
  if (lane < 16) {
    float di = dinv[wid];
    float d2 = di * di;
    float4 hv = H4[(size_t)wid * 16 + fl];
    float4 bv = bias4[fl];
    acc.x += hv.x * d2 + bv.x;
    acc.y += hv.y * d2 + bv.y;
    acc.z += hv.z * d2 + bv.z;
    acc.w += hv.w * d2 + bv.w;
    if (relu) {
      acc.x = fmaxf(acc.x, 0.f);
      acc.y = fmaxf(acc.y, 0.f);
      acc.z = fmaxf(acc.z, 0.f);
      acc.w = fmaxf(acc.w, 0.f);
    }
    OUT4[(size_t)wid * 16 + fl] = acc;  // 16 lanes x 16B = coalesced 256B row
  }
}

extern "C" void kernel_launch(void* const* d_in, const int* in_sizes, int n_in,
                              void* d_out, int out_size, void* d_ws, size_t ws_size,
                              hipStream_t stream) {
  const float* x  = (const float*)d_in[0];
  const int*   ei = (const int*)d_in[1];
  const float* W1 = (const float*)d_in[2];
  const float* b1 = (const float*)d_in[3];
  const float* W2 = (const float*)d_in[4];
  const float* b2 = (const float*)d_in[5];
  float* out = (float*)d_out;

  const int N = in_sizes[0] / 128;
  const int E = in_sizes[1] / 2;
  const int nbuck = (N + BUCKET - 1) / BUCKET;    // 782
  const int L = nbuck * NB_SCAT;                  // flat cell-hist length

  // ---- workspace carve-up (256B aligned) ----
  size_t off = 0;
  char* base = (char*)d_ws;
  auto alloc = [&](size_t bytes) -> void* {
    void* p = base + off;
    off += (bytes + 255) & ~(size_t)255;
    return p;
  };
  unsigned* flag  = (unsigned*)alloc(256);  // zeroed
  size_t zero_bytes = off;
  int*      hist  = (int*)alloc((size_t)L * 4);
  int*      shist = (int*)alloc((size_t)(L + 1) * 4);
  int*      cnt   = (int*)alloc((size_t)N * 4);
  int*      offs  = (int*)alloc((size_t)(N + 1) * 4);
  float*    dinv  = (float*)alloc((size_t)N * 4);
  int nb1 = (L + SCAN_BS - 1) / SCAN_BS;
  int nb2 = (N + SCAN_BS - 1) / SCAN_BS;
  int*      bsums = (int*)alloc((size_t)(nb1 > nb2 ? nb1 : nb2) * 4);
  unsigned* arr   = (unsigned*)alloc(((size_t)E + (size_t)PADREC * L) * 4);
  int2*     csr   = (int2*)alloc((size_t)E * 8);
  float*    h1    = (float*)alloc((size_t)N * 64 * 4);
  float*    a1    = (float*)alloc((size_t)N * 64 * 4);
  float*    h2    = h1;  // h1 dead after first aggregation

  hipMemsetAsync(d_ws, 0, zero_bytes, stream);

  int gemm_blocks = (N + 255) / 256;
  int agg_blocks = (N + 3) / 4;

  // ---- graph prep: single-owner CSR build (shared by both layers) ----
  detect_dtype_kernel<<<1, 256, 0, stream>>>((const unsigned*)ei, E, flag);
  histA_kernel<<<NB_SCAT, 256, 0, stream>>>(ei, E, flag, nbuck, hist);
  scan_block_kernel<<<nb1, SCAN_BS, 0, stream>>>(hist, L, bsums);
  scan_bsums_kernel<<<1, 512, 0, stream>>>(bsums, nb1);
  scan_apply_kernel<<<nb1, SCAN_BS, 0, stream>>>(hist, L, bsums, shist, nullptr);
  scatter_kernel<<<NB_SCAT, 256, 0, stream>>>(ei, E, flag, nbuck, shist, arr);
  degcnt_kernel<<<nbuck, 256, 0, stream>>>(arr, shist, N, cnt);
  scan_block_kernel<<<nb2, SCAN_BS, 0, stream>>>(cnt, N, bsums);
  scan_bsums_kernel<<<1, 512, 0, stream>>>(bsums, nb2);
  scan_apply_kernel<<<nb2, SCAN_BS, 0, stream>>>(cnt, N, bsums, offs, dinv);
  place_kernel<<<nbuck, 256, 0, stream>>>(arr, shist, offs, dinv, N, csr);

  // ---- layer 1 ----
  gemm_kernel<128><<<gemm_blocks, 256, 0, stream>>>(x, W1, h1, N);
  aggregate_kernel<<<agg_blocks, 256, 0, stream>>>(
      (const float4*)h1, offs, csr, dinv, (const float4*)b1, (float4*)a1, N, 1);

  // ---- layer 2 ----
  gemm_kernel<64><<<gemm_blocks, 256, 0, stream>>>(a1, W2, h2, N);
  aggregate_kernel<<<agg_blocks, 256, 0, stream>>>(
      (const float4*)h2, offs, csr, dinv, (const float4*)b2, (float4*)out, N, 0);
}

// Round 12
// 375.196 us; speedup vs baseline: 5.2913x; 1.0794x over previous
//
#include <hip/hip_runtime.h>

// MoleculeGCN: 2-layer GCN, N=100000, 128->64->64, E=1600000 + self-loops.
// r12 = r11 with the binning geometry widened for parallelism:
//   r11 counter evidence: scatter_kernel 65us at 2.5% occupancy (64 blocks),
//   WRITE_SIZE 8MB (single-owner scatter VALIDATED - was 102MB random).
//   Fix: 256 scatter blocks x 256-node bins (nbin=391, cells=100K, avg 16
//   records/cell, padding ~3MB) -> 4x parallelism, same single-owner property.
// Pipeline: detect -> histA -> scan(L) -> scatter(binned, single-owner) ->
// degcnt -> scan(N)+dinv -> place(bin-window CSR, single-owner) ->
// gemm1 -> agg1 -> gemm2 -> agg2.   Compute path = r6 proven (unchanged).

#define NB_SCAT 256     // blocks owning edge chunks (hist/scatter)
#define BINNODES 256    // nodes per scatter/place bin (bin = d>>8, dloc = d&255)
#define PADREC 16       // 4B recs per 64B line; cell padding granularity
#define SCAN_BS 256
#define INVALID_BIT (1u << 28)
#define SRC_MASK 0xFFFFFu   // 20 bits src; dloc in bits [20,28)

// ---------- edge dtype detect (int64 vs int32), SAMPLED ----------
__global__ __launch_bounds__(256) void detect_dtype_kernel(const unsigned* __restrict__ w,
                                                           int E, unsigned* __restrict__ flag) {
  __shared__ unsigned sacc;
  if (threadIdx.x == 0) sacc = 0u;
  __syncthreads();
  int ns = min(16384, E);
  unsigned acc = 0;
  for (int i = threadIdx.x; i < ns; i += 256) acc |= w[2 * i + 1];
  if (__any(acc != 0) && (threadIdx.x & 63) == 0) sacc = 1u;
  __syncthreads();
  if (threadIdx.x == 0) *flag = sacc;
}

__device__ __forceinline__ int edge_src(const int* w, int e, int E, bool is64) {
  return is64 ? w[2 * (long)e] : w[e];
}
__device__ __forceinline__ int edge_dst(const int* w, int e, int E, bool is64) {
  return is64 ? w[2 * ((long)E + e)] : w[(long)E + e];
}

// ---------- per-(bin,block) PADDED histogram, layout [bin][block] ----------
__global__ __launch_bounds__(256) void histA_kernel(const int* __restrict__ w, int E,
                                                    const unsigned* __restrict__ flag,
                                                    int nbin, int* __restrict__ hist) {
  __shared__ int h[1024];  // nbin <= 1024 (N <= 262144)
  bool is64 = (*flag == 0u);
  int i = blockIdx.x;
  int CH = (E + NB_SCAT - 1) / NB_SCAT;
  int e0 = i * CH, e1 = min(E, e0 + CH);
  for (int b = threadIdx.x; b < nbin; b += 256) h[b] = 0;
  __syncthreads();
  for (int e = e0 + threadIdx.x; e < e1; e += 256)
    atomicAdd(&h[edge_dst(w, e, E, is64) >> 8], 1);
  __syncthreads();
  for (int b = threadIdx.x; b < nbin; b += 256)
    hist[b * NB_SCAT + i] = (h[b] + PADREC - 1) & ~(PADREC - 1);  // 64B-pad cells
}

// ---------- generic exclusive scan (3 kernels, + sentinel out[n]=total) ----------
__global__ void scan_block_kernel(const int* __restrict__ cnt, int n, int* __restrict__ bsums) {
  __shared__ int s[SCAN_BS];
  int gid = blockIdx.x * SCAN_BS + threadIdx.x;
  s[threadIdx.x] = (gid < n) ? cnt[gid] : 0;
  __syncthreads();
  for (int st = SCAN_BS / 2; st > 0; st >>= 1) {
    if (threadIdx.x < st) s[threadIdx.x] += s[threadIdx.x + st];
    __syncthreads();
  }
  if (threadIdx.x == 0) bsums[blockIdx.x] = s[0];
}

__global__ __launch_bounds__(512) void scan_bsums_kernel(int* __restrict__ bsums, int nb) {
  __shared__ int s[512];
  int carry = 0;
  for (int base = 0; base < nb; base += 512) {
    int g = base + threadIdx.x;
    int v = (g < nb) ? bsums[g] : 0;
    s[threadIdx.x] = v;
    __syncthreads();
    for (int st = 1; st < 512; st <<= 1) {
      int t = (threadIdx.x >= st) ? s[threadIdx.x - st] : 0;
      __syncthreads();
      s[threadIdx.x] += t;
      __syncthreads();
    }
    if (g < nb) bsums[g] = carry + s[threadIdx.x] - v;
    carry += s[511];
    __syncthreads();
  }
}

// out = exclusive scan of cnt (+ out[n] = total). If dinv != nullptr, also
// dinv[gid] = rsqrt(cnt+1) (the +1 is the self loop).
__global__ void scan_apply_kernel(const int* __restrict__ cnt, int n,
                                  const int* __restrict__ bsums, int* __restrict__ out,
                                  float* __restrict__ dinv) {
  __shared__ int s[SCAN_BS];
  int gid = blockIdx.x * SCAN_BS + threadIdx.x;
  int v = (gid < n) ? cnt[gid] : 0;
  s[threadIdx.x] = v;
  __syncthreads();
  for (int st = 1; st < SCAN_BS; st <<= 1) {
    int t = (threadIdx.x >= st) ? s[threadIdx.x - st] : 0;
    __syncthreads();
    s[threadIdx.x] += t;
    __syncthreads();
  }
  if (gid < n) {
    int ex = bsums[blockIdx.x] + s[threadIdx.x] - v;
    out[gid] = ex;
    if (dinv) dinv[gid] = rsqrtf((float)v + 1.0f);
    if (gid == n - 1) out[n] = ex + v;  // sentinel
  }
}

// ---------- scatter to dense per-(bin,block) ranges (single-owner) ----------
__global__ __launch_bounds__(256) void scatter_kernel(const int* __restrict__ w, int E,
                                                      const unsigned* __restrict__ flag,
                                                      int nbin, const int* __restrict__ shist,
                                                      unsigned* __restrict__ arr) {
  __shared__ int cur[1024];
  bool is64 = (*flag == 0u);
  int i = blockIdx.x;
  for (int b = threadIdx.x; b < nbin; b += 256) cur[b] = shist[b * NB_SCAT + i];
  __syncthreads();
  int CH = (E + NB_SCAT - 1) / NB_SCAT;
  int e0 = i * CH, e1 = min(E, e0 + CH);
  for (int e = e0 + threadIdx.x; e < e1; e += 256) {
    int s = edge_src(w, e, E, is64);
    int d = edge_dst(w, e, E, is64);
    int p = atomicAdd(&cur[d >> 8], 1);  // LDS cursor
    arr[p] = (unsigned)s | ((unsigned)(d & 255) << 20);
  }
  __syncthreads();
  for (int b = threadIdx.x; b < nbin; b += 256) {
    int endp = shist[b * NB_SCAT + i + 1];  // next cell start (contiguous layout)
    for (int p = cur[b]; p < endp; p++) arr[p] = INVALID_BIT;  // sentinel fill
  }
}

// ---------- per-node degree counts from the binned array (no global atomics) ----
__global__ __launch_bounds__(256) void degcnt_kernel(const unsigned* __restrict__ arr,
                                                     const int* __restrict__ shist,
                                                     int N, int* __restrict__ cnt) {
  __shared__ int c[BINNODES];
  int b = blockIdx.x;
  for (int t = threadIdx.x; t < BINNODES; t += 256) c[t] = 0;
  __syncthreads();
  int eb = shist[b * NB_SCAT], ee = shist[(b + 1) * NB_SCAT];
  for (int p = eb + threadIdx.x; p < ee; p += 256) {
    unsigned r = arr[p];
    if (!(r & INVALID_BIT)) atomicAdd(&c[(r >> 20) & 255], 1);
  }
  __syncthreads();
  int g = b * BINNODES + threadIdx.x;
  if (g < N) cnt[g] = c[threadIdx.x];
}

// ---------- place: bin-window CSR build (single-owner lines) ----------
// Block b owns CSR window [offs[b*256], offs[(b+1)*256)) ~32KB: all its lines
// written only by this block -> L2 accumulates full lines before writeback.
__global__ __launch_bounds__(256) void place_kernel(
    const unsigned* __restrict__ arr, const int* __restrict__ shist,
    const int* __restrict__ offs, const float* __restrict__ dinv,
    int N, int2* __restrict__ csr) {
  __shared__ int lfill[BINNODES];
  __shared__ int loffs[BINNODES];
  __shared__ float dl[BINNODES];
  int b = blockIdx.x, d0 = b * BINNODES;
  for (int t = threadIdx.x; t < BINNODES; t += 256) {
    lfill[t] = 0;
    int g = d0 + t;
    loffs[t] = (g < N) ? offs[g] : 0;
    dl[t] = (g < N) ? dinv[g] : 0.f;
  }
  __syncthreads();
  int eb = shist[b * NB_SCAT], ee = shist[(b + 1) * NB_SCAT];
  for (int p = eb + threadIdx.x; p < ee; p += 256) {
    unsigned r = arr[p];
    if (r & INVALID_BIT) continue;
    int s = r & SRC_MASK;
    int dloc = (r >> 20) & 255;
    int pos = loffs[dloc] + atomicAdd(&lfill[dloc], 1);
    int2 rec;
    rec.x = s;
    rec.y = __float_as_int(dinv[s] * dl[dloc]);
    csr[pos] = rec;
  }
}

// ---------- GEMM: H[n][64] = X[n][K] @ W[K][64], W staged in LDS (r6 proven) ----------
template <int K>
__global__ __launch_bounds__(256) void gemm_kernel(const float* __restrict__ X,
                                                   const float* __restrict__ W,
                                                   float* __restrict__ H, int n) {
  __shared__ float Ws[K * 64];
  for (int i = threadIdx.x; i < K * 64; i += 256) Ws[i] = W[i];
  __syncthreads();
  int row = blockIdx.x * 256 + threadIdx.x;
  if (row >= n) return;
  const float4* xr = (const float4*)(X + (size_t)row * K);
  float acc[64];
#pragma unroll
  for (int c = 0; c < 64; c++) acc[c] = 0.f;
#pragma unroll 4
  for (int k4 = 0; k4 < K / 4; k4++) {
    float4 xv = xr[k4];
#pragma unroll
    for (int kk = 0; kk < 4; kk++) {
      float xs = (kk == 0) ? xv.x : (kk == 1) ? xv.y : (kk == 2) ? xv.z : xv.w;
      const float4* wr = (const float4*)&Ws[(k4 * 4 + kk) * 64];
#pragma unroll
      for (int c4 = 0; c4 < 16; c4++) {
        float4 wv = wr[c4];  // same address across lanes -> LDS broadcast
        acc[c4 * 4 + 0] += xs * wv.x;
        acc[c4 * 4 + 1] += xs * wv.y;
        acc[c4 * 4 + 2] += xs * wv.z;
        acc[c4 * 4 + 3] += xs * wv.w;
      }
    }
  }
  float4* ho = (float4*)(H + (size_t)row * 64);
#pragma unroll
  for (int c4 = 0; c4 < 16; c4++) {
    float4 v;
    v.x = acc[c4 * 4 + 0]; v.y = acc[c4 * 4 + 1];
    v.z = acc[c4 * 4 + 2]; v.w = acc[c4 * 4 + 3];
    ho[c4] = v;
  }
}

// ---------- aggregation (r6 proven): wave per node, 4 groups x 16 lanes x float4 ----
__global__ __launch_bounds__(256) void aggregate_kernel(
    const float4* __restrict__ H4, const int* __restrict__ offs,
    const int2* __restrict__ csr,
    const float* __restrict__ dinv, const float4* __restrict__ bias4,
    float4* __restrict__ OUT4, int n, int relu) {
  int wid = (blockIdx.x * 256 + threadIdx.x) >> 6;
  int lane = threadIdx.x & 63;
  if (wid >= n) return;
  int grp = lane >> 4;
  int fl = lane & 15;
  int beg = offs[wid];
  int end = offs[wid + 1];
  float4 acc = {0.f, 0.f, 0.f, 0.f};
  for (int base = beg; base < end; base += 64) {
    int m = min(64, end - base);
    int sl = 0; float nl = 0.f;
    if (lane < m) {
      int2 rec = csr[base + lane];  // coalesced 8B
      sl = rec.x;
      nl = __int_as_float(rec.y);
    }
    int iters = ((m + 31) >> 5) << 3;  // 8 or 16; each iter covers 4 edges
    for (int j0 = 0; j0 < iters; j0 += 8) {
      int s[8]; float w[8]; float4 h[8];
#pragma unroll
      for (int t = 0; t < 8; t++) {
        int idx = (j0 + t) * 4 + grp;  // uniform within each 16-lane group
        s[t] = __shfl(sl, idx);
        w[t] = __shfl(nl, idx);
      }
#pragma unroll
      for (int t = 0; t < 8; t++) h[t] = H4[(size_t)s[t] * 16 + fl];  // 8 in flight
#pragma unroll
      for (int t = 0; t < 8; t++) {
        acc.x += h[t].x * w[t];
        acc.y += h[t].y * w[t];
        acc.z += h[t].z * w[t];
        acc.w += h[t].w * w[t];
      }
    }
  }
#pragma unroll
  for (int off2 = 32; off2 >= 16; off2 >>= 1) {
    acc.x += __shfl_xor(acc.x, off2);
    acc.y += __shfl_xor(acc.y, off2);
    acc.z += __shfl_xor(acc.z, off2);
    acc.w += __shfl_xor(acc.w, off2);
  }
  if (lane < 16) {
    float di = dinv[wid];
    float d2 = di * di;
    float4 hv = H4[(size_t)wid * 16 + fl];
    float4 bv = bias4[fl];
    acc.x += hv.x * d2 + bv.x;
    acc.y += hv.y * d2 + bv.y;
    acc.z += hv.z * d2 + bv.z;
    acc.w += hv.w * d2 + bv.w;
    if (relu) {
      acc.x = fmaxf(acc.x, 0.f);
      acc.y = fmaxf(acc.y, 0.f);
      acc.z = fmaxf(acc.z, 0.f);
      acc.w = fmaxf(acc.w, 0.f);
    }
    OUT4[(size_t)wid * 16 + fl] = acc;  // 16 lanes x 16B = coalesced 256B row
  }
}

extern "C" void kernel_launch(void* const* d_in, const int* in_sizes, int n_in,
                              void* d_out, int out_size, void* d_ws, size_t ws_size,
                              hipStream_t stream) {
  const float* x  = (const float*)d_in[0];
  const int*   ei = (const int*)d_in[1];
  const float* W1 = (const float*)d_in[2];
  const float* b1 = (const float*)d_in[3];
  const float* W2 = (const float*)d_in[4];
  const float* b2 = (const float*)d_in[5];
  float* out = (float*)d_out;

  const int N = in_sizes[0] / 128;
  const int E = in_sizes[1] / 2;
  const int nbin = (N + BINNODES - 1) / BINNODES;  // 391
  const int L = nbin * NB_SCAT;                    // ~100K cells

  // ---- workspace carve-up (256B aligned) ----
  size_t off = 0;
  char* base = (char*)d_ws;
  auto alloc = [&](size_t bytes) -> void* {
    void* p = base + off;
    off += (bytes + 255) & ~(size_t)255;
    return p;
  };
  unsigned* flag  = (unsigned*)alloc(256);  // zeroed
  size_t zero_bytes = off;
  int*      hist  = (int*)alloc((size_t)L * 4);
  int*      shist = (int*)alloc((size_t)(L + 1) * 4);
  int*      cnt   = (int*)alloc((size_t)N * 4);
  int*      offs  = (int*)alloc((size_t)(N + 1) * 4);
  float*    dinv  = (float*)alloc((size_t)N * 4);
  int nb1 = (L + SCAN_BS - 1) / SCAN_BS;
  int nb2 = (N + SCAN_BS - 1) / SCAN_BS;
  int*      bsums = (int*)alloc((size_t)(nb1 > nb2 ? nb1 : nb2) * 4);
  unsigned* arr   = (unsigned*)alloc(((size_t)E + (size_t)PADREC * L) * 4);
  int2*     csr   = (int2*)alloc((size_t)E * 8);
  float*    h1    = (float*)alloc((size_t)N * 64 * 4);
  float*    a1    = (float*)alloc((size_t)N * 64 * 4);
  float*    h2    = h1;  // h1 dead after first aggregation

  hipMemsetAsync(d_ws, 0, zero_bytes, stream);

  int gemm_blocks = (N + 255) / 256;
  int agg_blocks = (N + 3) / 4;

  // ---- graph prep: single-owner CSR build (shared by both layers) ----
  detect_dtype_kernel<<<1, 256, 0, stream>>>((const unsigned*)ei, E, flag);
  histA_kernel<<<NB_SCAT, 256, 0, stream>>>(ei, E, flag, nbin, hist);
  scan_block_kernel<<<nb1, SCAN_BS, 0, stream>>>(hist, L, bsums);
  scan_bsums_kernel<<<1, 512, 0, stream>>>(bsums, nb1);
  scan_apply_kernel<<<nb1, SCAN_BS, 0, stream>>>(hist, L, bsums, shist, nullptr);
  scatter_kernel<<<NB_SCAT, 256, 0, stream>>>(ei, E, flag, nbin, shist, arr);
  degcnt_kernel<<<nbin, 256, 0, stream>>>(arr, shist, N, cnt);
  scan_block_kernel<<<nb2, SCAN_BS, 0, stream>>>(cnt, N, bsums);
  scan_bsums_kernel<<<1, 512, 0, stream>>>(bsums, nb2);
  scan_apply_kernel<<<nb2, SCAN_BS, 0, stream>>>(cnt, N, bsums, offs, dinv);
  place_kernel<<<nbin, 256, 0, stream>>>(arr, shist, offs, dinv, N, csr);

  // ---- layer 1 ----
  gemm_kernel<128><<<gemm_blocks, 256, 0, stream>>>(x, W1, h1, N);
  aggregate_kernel<<<agg_blocks, 256, 0, stream>>>(
      (const float4*)h1, offs, csr, dinv, (const float4*)b1, (float4*)a1, N, 1);

  // ---- layer 2 ----
  gemm_kernel<64><<<gemm_blocks, 256, 0, stream>>>(a1, W2, h2, N);
  aggregate_kernel<<<agg_blocks, 256, 0, stream>>>(
      (const float4*)h2, offs, csr, dinv, (const float4*)b2, (float4*)out, N, 0);
}